// Round 3
// baseline (187.227 us; speedup 1.0000x reference)
//
#include <hip/hip_runtime.h>
#include <hip/hip_bf16.h>

#define B_   8
#define TQ_  100
#define TS_  100
#define E_   512
#define D_   512
#define K_   1024
#define M_   (B_*TQ_*TS_)   // 80000

#define MT   128            // M-tile per block (625 blocks)
#define NT   512            // full N per block
#define BK   64             // K per staged step (16 steps)
#define NTHREADS 512        // 8 waves (2M x 4N)

typedef __attribute__((ext_vector_type(4))) float f32x4;
typedef __attribute__((ext_vector_type(8))) short bf16x8;

__device__ __forceinline__ short f2bf(float f) {
  __hip_bfloat16 h = __float2bfloat16(f);
  return *reinterpret_cast<short*>(&h);
}

__device__ __forceinline__ float fast_tanh(float x) {
  float e = __expf(2.0f * x);
  return 1.0f - 2.0f / (e + 1.0f);
}

__device__ __forceinline__ void gld16(const void* g, void* l) {
  __builtin_amdgcn_global_load_lds(
      (const __attribute__((address_space(1))) unsigned int*)g,
      (__attribute__((address_space(3))) unsigned int*)l, 16, 0, 0);
}

// ---- prep: W1 [K=1024][D=512] f32 -> W1sw bf16 [n=512][k=1024], XOR-preswizzled
// (element (n,k) at byte (k*2)^((n&7)<<4) within its row) so that a LINEAR
// global_load_lds of any 128B row-segment lands such that ds_read at
// (n*128 + (kb ^ ((n&7)<<4))) returns element k0 + kb/2.
__global__ void prep_w1(const float* __restrict__ W1, short* __restrict__ W1sw) {
  int idx = blockIdx.x * 256 + threadIdx.x;   // over K_*D_
  int k = idx >> 9;          // /512
  int n = idx & (D_ - 1);
  int byte = (k * 2) ^ ((n & 7) << 4);
  W1sw[(size_t)n * K_ + (byte >> 1)] = f2bf(W1[idx]);
}

// ---- kernel 1: scores[m] = sum_n w2[n]*tanh(cat[m,:].W1[:,n] + b1[n]) ----
__launch_bounds__(NTHREADS, 2)
__global__ void scores_kernel(const float* __restrict__ src,
                              const float* __restrict__ tgt,
                              const short* __restrict__ W1sw,
                              const float* __restrict__ b1,
                              const float* __restrict__ w2,
                              float* __restrict__ scores) {
  __shared__ __align__(16) char Alds[2][MT * 128];   // 2 x 16 KB
  __shared__ __align__(16) char Blds[2][NT * 128];   // 2 x 64 KB  (total 160 KB)

  const int tid  = threadIdx.x;
  const int wave = tid >> 6;
  const int lane = tid & 63;
  const int lr   = lane & 15;      // fragment row/col
  const int lg   = lane >> 4;      // k-octet group
  const int wr   = wave >> 2;      // wave M index (0..1)  -> rows wr*64..+64
  const int wc   = wave & 3;       // wave N index (0..3)  -> cols wc*128..+128
  const int m0   = blockIdx.x * MT;

  f32x4 acc[4][8];
  #pragma unroll
  for (int i = 0; i < 4; i++)
    #pragma unroll
    for (int j = 0; j < 8; j++)
      acc[i][j] = (f32x4){0.f, 0.f, 0.f, 0.f};

  // A-stage mapping: thread -> (row ra, 16 consecutive k at ka)
  const int ra  = tid >> 2;            // 0..127
  const int ka  = (tid & 3) * 16;      // 0,16,32,48
  const int swA = (ra & 7) << 4;
  // B-stage mapping: 8 gld16 rounds; round j covers rows j*64..j*64+63
  const int br = tid >> 3;             // 0..63
  const int bb = (tid & 7) * 16;       // byte within 128B row

  #define ISSUE_A(R0,R1,R2,R3,K0)                                              \
    {                                                                          \
      const float* Ap = (((K0) < E_) ? src : tgt)                              \
                        + (size_t)(m0 + ra) * E_ + ((K0) & (E_ - 1)) + ka;     \
      R0 = *reinterpret_cast<const f32x4*>(Ap);                                \
      R1 = *reinterpret_cast<const f32x4*>(Ap + 4);                            \
      R2 = *reinterpret_cast<const f32x4*>(Ap + 8);                            \
      R3 = *reinterpret_cast<const f32x4*>(Ap + 12);                           \
    }

  #define WRITE_A(R0,R1,R2,R3,BUF)                                             \
    {                                                                          \
      bf16x8 w0, w1;                                                           \
      w0[0]=f2bf(R0[0]); w0[1]=f2bf(R0[1]); w0[2]=f2bf(R0[2]); w0[3]=f2bf(R0[3]);\
      w0[4]=f2bf(R1[0]); w0[5]=f2bf(R1[1]); w0[6]=f2bf(R1[2]); w0[7]=f2bf(R1[3]);\
      w1[0]=f2bf(R2[0]); w1[1]=f2bf(R2[1]); w1[2]=f2bf(R2[2]); w1[3]=f2bf(R2[3]);\
      w1[4]=f2bf(R3[0]); w1[5]=f2bf(R3[1]); w1[6]=f2bf(R3[2]); w1[7]=f2bf(R3[3]);\
      int kb = ka * 2;                                                         \
      *reinterpret_cast<bf16x8*>((BUF) + ra * 128 + ( kb       ^ swA)) = w0;   \
      *reinterpret_cast<bf16x8*>((BUF) + ra * 128 + ((kb + 16) ^ swA)) = w1;   \
    }

  #define ISSUE_B(K0,BUF)                                                      \
    {                                                                          \
      _Pragma("unroll")                                                        \
      for (int j = 0; j < 8; j++) {                                            \
        const char* gp = (const char*)W1sw + (size_t)(j * 64 + br) * 2048      \
                         + (size_t)(K0) * 2 + bb;                              \
        gld16(gp, (BUF) + j * 8192 + tid * 16);                                \
      }                                                                        \
    }

  #define MFMA_PHASE(KK,AB,BB2)                                                \
    {                                                                          \
      const int kb = (KK) * 64 + lg * 16;                                      \
      bf16x8 a[4], b[8];                                                       \
      _Pragma("unroll")                                                        \
      for (int mi = 0; mi < 4; mi++) {                                         \
        int row = wr * 64 + mi * 16 + lr;                                      \
        a[mi] = *reinterpret_cast<const bf16x8*>(                              \
                    (AB) + row * 128 + (kb ^ ((row & 7) << 4)));               \
      }                                                                        \
      _Pragma("unroll")                                                        \
      for (int ni = 0; ni < 8; ni++) {                                         \
        int nr = wc * 128 + ni * 16 + lr;                                      \
        b[ni] = *reinterpret_cast<const bf16x8*>(                              \
                    (BB2) + nr * 128 + (kb ^ ((nr & 7) << 4)));                \
      }                                                                        \
      __builtin_amdgcn_s_setprio(1);                                           \
      _Pragma("unroll")                                                        \
      for (int mi = 0; mi < 4; mi++)                                           \
        _Pragma("unroll")                                                      \
        for (int ni = 0; ni < 8; ni++)                                         \
          acc[mi][ni] = __builtin_amdgcn_mfma_f32_16x16x32_bf16(               \
                            a[mi], b[ni], acc[mi][ni], 0, 0, 0);               \
      __builtin_amdgcn_s_setprio(0);                                           \
    }

  // ---- prologue: stage tile 0 into buffer 0 ----
  {
    f32x4 r0, r1, r2, r3;
    ISSUE_A(r0, r1, r2, r3, 0);
    ISSUE_B(0, Blds[0]);
    WRITE_A(r0, r1, r2, r3, Alds[0]);
  }
  __syncthreads();   // drains vmcnt(0)+lgkmcnt(0): tile 0 fully staged

  for (int t = 0; t < 16; ++t) {
    const int cur = t & 1;
    const int nxt = cur ^ 1;
    const bool pf = (t < 15);
    const int k0n = (t + 1) * BK;
    f32x4 r0, r1, r2, r3;
    if (pf) ISSUE_A(r0, r1, r2, r3, k0n);        // HBM loads first (longest)
    MFMA_PHASE(0, Alds[cur], Blds[cur]);
    if (pf) {
      ISSUE_B(k0n, Blds[nxt]);                   // L2-resident, ~1 phase ahead
      WRITE_A(r0, r1, r2, r3, Alds[nxt]);
    }
    MFMA_PHASE(1, Alds[cur], Blds[cur]);
    __syncthreads();   // single barrier per K-step; drains gld16 into nxt
  }

  // ---- epilogue: scores[m] = sum_n w2[n]*tanh(h[m,n]+b1[n]) ----
  float* s_sc = (float*)Alds;   // reuse A buffer
  if (tid < MT) s_sc[tid] = 0.0f;
  __syncthreads();

  float b1v[8], w2v[8];
  #pragma unroll
  for (int ni = 0; ni < 8; ni++) {
    int n = wc * 128 + ni * 16 + lr;
    b1v[ni] = b1[n];
    w2v[ni] = w2[n];
  }
  #pragma unroll
  for (int mi = 0; mi < 4; mi++) {
    #pragma unroll
    for (int r = 0; r < 4; r++) {
      float p = 0.0f;
      #pragma unroll
      for (int ni = 0; ni < 8; ni++)
        p += fast_tanh(acc[mi][ni][r] + b1v[ni]) * w2v[ni];
      p += __shfl_xor(p, 1);
      p += __shfl_xor(p, 2);
      p += __shfl_xor(p, 4);
      p += __shfl_xor(p, 8);
      if (lr == 0) atomicAdd(&s_sc[wr * 64 + mi * 16 + lg * 4 + r], p);
    }
  }
  __syncthreads();
  if (tid < MT) scores[m0 + tid] = s_sc[tid];
}

// ---- kernel 2: mask, softmax over s, weights out, weighted sum over src ----
__global__ void softmax_wsum(const float* __restrict__ src,
                             const float* __restrict__ mask,
                             const float* __restrict__ scores,
                             float* __restrict__ out) {
  const int row = blockIdx.x;     // b*TQ+q, 0..799
  const int tid = threadIdx.x;    // 512 threads
  __shared__ float s_e[TS_];

  float v = 0.0f;
  if (tid < TS_) {
    v = scores[row * TS_ + tid] * mask[row * TS_ + tid];
    s_e[tid] = v;
  }
  __syncthreads();
  float mx = -3.0e38f;
  for (int s = 0; s < TS_; s++) mx = fmaxf(mx, s_e[s]);   // LDS broadcast
  __syncthreads();
  if (tid < TS_) s_e[tid] = __expf(v - mx);
  __syncthreads();
  float sum = 0.0f;
  for (int s = 0; s < TS_; s++) sum += s_e[s];
  const float inv = 1.0f / sum;

  float* out_attn = out;                          // [800][512]
  float* out_w    = out + (size_t)B_ * TQ_ * E_;  // [800][100]
  if (tid < TS_) out_w[row * TS_ + tid] = s_e[tid] * inv;

  const float* sp = src + (size_t)row * TS_ * E_ + tid;  // thread owns dim e=tid
  float acc = 0.0f;
  #pragma unroll 4
  for (int s = 0; s < TS_; s++) acc = fmaf(s_e[s], sp[(size_t)s * E_], acc);
  out_attn[row * E_ + tid] = acc * inv;
}

extern "C" void kernel_launch(void* const* d_in, const int* in_sizes, int n_in,
                              void* d_out, int out_size, void* d_ws, size_t ws_size,
                              hipStream_t stream) {
  const float* src  = (const float*)d_in[0];
  const float* tgt  = (const float*)d_in[1];
  const float* mask = (const float*)d_in[2];
  const float* W1   = (const float*)d_in[3];
  const float* b1   = (const float*)d_in[4];
  const float* w2   = (const float*)d_in[5];

  short* W1sw   = (short*)d_ws;                                // 1 MB
  float* scores = (float*)((char*)d_ws + (size_t)D_ * K_ * 2); // 80000 f32

  float* out = (float*)d_out;

  hipLaunchKernelGGL(prep_w1, dim3((K_ * D_) / 256), dim3(256), 0, stream, W1, W1sw);
  hipLaunchKernelGGL(scores_kernel, dim3(M_ / MT), dim3(NTHREADS), 0, stream,
                     src, tgt, W1sw, b1, w2, scores);
  hipLaunchKernelGGL(softmax_wsum, dim3(B_ * TQ_), dim3(512), 0, stream,
                     src, mask, scores, out);
}

// Round 4
// 180.352 us; speedup vs baseline: 1.0381x; 1.0381x over previous
//
#include <hip/hip_runtime.h>
#include <hip/hip_bf16.h>

#define B_   8
#define TQ_  100
#define TS_  100
#define E_   512
#define D_   512
#define K_   1024
#define M_   (B_*TQ_*TS_)   // 80000

#define MT   64             // M-tile per block (1250 blocks)
#define NCH  32             // K chunks of 32
#define NTHREADS 512        // 8 waves, 1M x 8N (wave w owns cols w*64..+64)

typedef __attribute__((ext_vector_type(4))) float f32x4;
typedef __attribute__((ext_vector_type(8))) short bf16x8;
typedef __attribute__((ext_vector_type(4))) short bf16x4;

__device__ __forceinline__ short f2bf(float f) {
  __hip_bfloat16 h = __float2bfloat16(f);
  return *reinterpret_cast<short*>(&h);
}

__device__ __forceinline__ float fast_tanh(float x) {
  float e = __expf(2.0f * x);
  return 1.0f - 2.0f / (e + 1.0f);
}

__device__ __forceinline__ void gld16(const void* g, void* l) {
  __builtin_amdgcn_global_load_lds(
      (const __attribute__((address_space(1))) unsigned int*)g,
      (__attribute__((address_space(3))) unsigned int*)l, 16, 0, 0);
}

__device__ __forceinline__ bf16x4 packA(f32x4 v) {
  bf16x4 o;
  o[0] = f2bf(v[0]); o[1] = f2bf(v[1]); o[2] = f2bf(v[2]); o[3] = f2bf(v[3]);
  return o;
}

// ---- prep: W1 [k=1024][n=512] f32 -> W1sw2, per-chunk packed + slot-swizzled.
// Chunk c holds k=32c..32c+31 for all n: 512 rows x 4 slots x 16B (32KB).
// Slot s of row n holds k-octet (s ^ (n&3)); gld16 loads it LINEARLY, and
// ds_read at byte (lg*16)^((n&3)<<4) returns k-octet lg (k = 32c+8lg..+8).
__global__ void prep_w1(const float* __restrict__ W1, short* __restrict__ W1sw2) {
  int idx = blockIdx.x * 256 + threadIdx.x;   // over K_*D_ = 524288
  int k = idx >> 9;            // 0..1023
  int n = idx & (D_ - 1);      // 0..511
  int c = k >> 5;              // chunk
  int o = (k >> 3) & 3;        // k-octet within chunk
  int w = k & 7;               // element within octet
  int slot = o ^ (n & 3);
  W1sw2[((size_t)c << 14) + (size_t)((n * 4 + slot) << 3) + w] = f2bf(W1[idx]);
}

// ---- kernel 1: scores[m] = sum_n w2[n]*tanh(cat[m,:].W1[:,n] + b1[n]) ----
__launch_bounds__(NTHREADS, 4)
__global__ void scores_kernel(const float* __restrict__ src,
                              const float* __restrict__ tgt,
                              const short* __restrict__ W1sw2,
                              const float* __restrict__ b1,
                              const float* __restrict__ w2,
                              float* __restrict__ scores) {
  __shared__ __align__(16) char Alds[3][MT * 64];    // 3 x 4 KB (triple buffer)
  __shared__ __align__(16) char Blds[2][D_ * 64];    // 2 x 32 KB -> total 76 KB

  const int tid  = threadIdx.x;
  const int wave = tid >> 6;
  const int lane = tid & 63;
  const int lr   = lane & 15;
  const int lg   = lane >> 4;
  const int m0   = blockIdx.x * MT;
  const int boff = (lg * 16) ^ ((lr & 3) << 4);   // frag read byte offset

  // A staging: thread -> row ra (8 thr/row), 4 consecutive floats at kaf
  const int ra    = tid >> 3;                      // 0..63
  const int kaf   = (tid & 7) * 4;                 // float offset in 32-k chunk
  const int awoff = ra * 64 + (((tid & 7) * 8) ^ ((ra & 3) << 4));
  const size_t rowoff = (size_t)(m0 + ra) * E_;

  f32x4 acc[4][4];
  #pragma unroll
  for (int i = 0; i < 4; i++)
    #pragma unroll
    for (int j = 0; j < 4; j++)
      acc[i][j] = (f32x4){0.f, 0.f, 0.f, 0.f};

  #define APTR(T) ((const f32x4*)((((T) < 16) ? src : tgt) + rowoff + (((T) * 32) & 511) + kaf))

  #define ISSUE_B(CC, BUF)                                                     \
    { const char* gb = (const char*)W1sw2 + ((size_t)(CC) << 15) + tid * 16;   \
      _Pragma("unroll")                                                        \
      for (int j = 0; j < 4; j++)                                              \
        gld16(gb + j * 8192, (BUF) + j * 8192 + wave * 1024); }

  #define COMPUTE(AR, BBUF)                                                    \
    { bf16x8 a[4], b[4];                                                       \
      _Pragma("unroll")                                                        \
      for (int mi = 0; mi < 4; mi++)                                           \
        a[mi] = *(const bf16x8*)(Alds[AR] + (mi * 16 + lr) * 64 + boff);       \
      _Pragma("unroll")                                                        \
      for (int ni = 0; ni < 4; ni++)                                           \
        b[ni] = *(const bf16x8*)((BBUF) + (wave * 64 + ni * 16 + lr) * 64 + boff); \
      __builtin_amdgcn_s_setprio(1);                                           \
      _Pragma("unroll")                                                        \
      for (int mi = 0; mi < 4; mi++)                                           \
        _Pragma("unroll")                                                      \
        for (int ni = 0; ni < 4; ni++)                                         \
          acc[mi][ni] = __builtin_amdgcn_mfma_f32_16x16x32_bf16(               \
                            a[mi], b[ni], acc[mi][ni], 0, 0, 0);               \
      __builtin_amdgcn_s_setprio(0); }

  // body(c): ds_write A[c+1] | issue B[c+1] | issue A[c+2] | compute c |
  //          vmcnt(1): B[c+1] landed, A[c+2] stays in flight across barrier
  #define BODY(AR, AW, BR, RW, RI, CC)                                         \
    {                                                                          \
      *(bf16x4*)(Alds[AW] + awoff) = packA(RW);                                \
      ISSUE_B((CC) + 1, Blds[(BR) ^ 1]);                                       \
      __builtin_amdgcn_sched_barrier(0);                                       \
      RI = *APTR((CC) + 2);                                                    \
      COMPUTE(AR, Blds[BR]);                                                   \
      asm volatile("s_waitcnt vmcnt(1) lgkmcnt(0)" ::: "memory");              \
      __builtin_amdgcn_sched_barrier(0);                                       \
      __builtin_amdgcn_s_barrier();                                            \
      __builtin_amdgcn_sched_barrier(0);                                       \
    }

  f32x4 r0, r1;
  // ---- prologue: B[0], A[0], A[1]; write A[0]; B[0]+A[0] drained ----
  ISSUE_B(0, Blds[0]);
  __builtin_amdgcn_sched_barrier(0);
  r0 = *APTR(0);
  r1 = *APTR(1);
  *(bf16x4*)(Alds[0] + awoff) = packA(r0);
  asm volatile("s_waitcnt vmcnt(1) lgkmcnt(0)" ::: "memory");
  __builtin_amdgcn_sched_barrier(0);
  __builtin_amdgcn_s_barrier();
  __builtin_amdgcn_sched_barrier(0);

  // ---- main: chunks 0..29, period-6 static unroll ----
  for (int i = 0; i < 5; ++i) {
    const int c = 6 * i;
    BODY(0, 1, 0, r1, r0, c + 0);
    BODY(1, 2, 1, r0, r1, c + 1);
    BODY(2, 0, 0, r1, r0, c + 2);
    BODY(0, 1, 1, r0, r1, c + 3);
    BODY(1, 2, 0, r1, r0, c + 4);
    BODY(2, 0, 1, r0, r1, c + 5);
  }

  // ---- epilogue: chunk 30 (stage B[31], write A[31]), chunk 31 ----
  {
    *(bf16x4*)(Alds[1] + awoff) = packA(r1);   // A[31] -> Alds[31%3=1]
    ISSUE_B(31, Blds[1]);
    COMPUTE(0, Blds[0]);                       // chunk 30: A 30%3=0, B 30&1=0
    asm volatile("s_waitcnt vmcnt(0) lgkmcnt(0)" ::: "memory");
    __builtin_amdgcn_sched_barrier(0);
    __builtin_amdgcn_s_barrier();
    __builtin_amdgcn_sched_barrier(0);
    COMPUTE(1, Blds[1]);                       // chunk 31
  }

  // ---- score epilogue ----
  float* s_sc = (float*)Blds[0];   // B buffers done; safe scratch
  __builtin_amdgcn_s_barrier();    // all waves done with final frag reads
  if (tid < MT) s_sc[tid] = 0.0f;
  __syncthreads();

  float b1v[4], w2v[4];
  #pragma unroll
  for (int ni = 0; ni < 4; ni++) {
    int n = wave * 64 + ni * 16 + lr;
    b1v[ni] = b1[n];
    w2v[ni] = w2[n];
  }
  #pragma unroll
  for (int mi = 0; mi < 4; mi++) {
    #pragma unroll
    for (int r = 0; r < 4; r++) {
      float p = 0.0f;
      #pragma unroll
      for (int ni = 0; ni < 4; ni++)
        p += fast_tanh(acc[mi][ni][r] + b1v[ni]) * w2v[ni];
      p += __shfl_xor(p, 1);
      p += __shfl_xor(p, 2);
      p += __shfl_xor(p, 4);
      p += __shfl_xor(p, 8);
      if (lr == 0) atomicAdd(&s_sc[mi * 16 + lg * 4 + r], p);
    }
  }
  __syncthreads();
  if (tid < MT) scores[m0 + tid] = s_sc[tid];
}

// ---- kernel 2: mask, softmax over s, weights out, weighted sum over src ----
__global__ void softmax_wsum(const float* __restrict__ src,
                             const float* __restrict__ mask,
                             const float* __restrict__ scores,
                             float* __restrict__ out) {
  const int row = blockIdx.x;     // b*TQ+q, 0..799
  const int tid = threadIdx.x;    // 512 threads
  __shared__ float s_e[TS_];

  float v = 0.0f;
  if (tid < TS_) {
    v = scores[row * TS_ + tid] * mask[row * TS_ + tid];
    s_e[tid] = v;
  }
  __syncthreads();
  float mx = -3.0e38f;
  for (int s = 0; s < TS_; s++) mx = fmaxf(mx, s_e[s]);
  __syncthreads();
  if (tid < TS_) s_e[tid] = __expf(v - mx);
  __syncthreads();
  float sum = 0.0f;
  for (int s = 0; s < TS_; s++) sum += s_e[s];
  const float inv = 1.0f / sum;

  float* out_attn = out;                          // [800][512]
  float* out_w    = out + (size_t)B_ * TQ_ * E_;  // [800][100]
  if (tid < TS_) out_w[row * TS_ + tid] = s_e[tid] * inv;

  const float* sp = src + (size_t)row * TS_ * E_ + tid;
  float acc = 0.0f;
  #pragma unroll 4
  for (int s = 0; s < TS_; s++) acc = fmaf(s_e[s], sp[(size_t)s * E_], acc);
  out_attn[row * E_ + tid] = acc * inv;
}

extern "C" void kernel_launch(void* const* d_in, const int* in_sizes, int n_in,
                              void* d_out, int out_size, void* d_ws, size_t ws_size,
                              hipStream_t stream) {
  const float* src  = (const float*)d_in[0];
  const float* tgt  = (const float*)d_in[1];
  const float* mask = (const float*)d_in[2];
  const float* W1   = (const float*)d_in[3];
  const float* b1   = (const float*)d_in[4];
  const float* w2   = (const float*)d_in[5];

  short* W1sw2  = (short*)d_ws;                                // 1 MB
  float* scores = (float*)((char*)d_ws + (size_t)D_ * K_ * 2); // 80000 f32

  float* out = (float*)d_out;

  hipLaunchKernelGGL(prep_w1, dim3((K_ * D_) / 256), dim3(256), 0, stream, W1, W1sw2);
  hipLaunchKernelGGL(scores_kernel, dim3(M_ / MT), dim3(NTHREADS), 0, stream,
                     src, tgt, W1sw2, b1, w2, scores);
  hipLaunchKernelGGL(softmax_wsum, dim3(B_ * TQ_), dim3(512), 0, stream,
                     src, mask, scores, out);
}